// Round 9
// baseline (405.825 us; speedup 1.0000x reference)
//
#include <hip/hip_runtime.h>

// Problem dims
#define H_  256
#define I_  128
#define R_  32
#define B_  16
#define T_  48
#define H3_ 768

// d_out float offsets: (v, h, dU, trace_e, trace_E, outs, mods)
#define OFF_V    0
#define OFF_H    4096
#define OFF_DU   8192
#define OFF_TE   1056768
#define OFF_TT   1060864
#define OFF_OUTS 2109440
#define OFF_MODS 2306048

#define BAR_STRIDE 32          // ints; 128B between per-group structures

// Module-static scratch (allocated at .so load; zero-init counters).
__device__ __align__(16) float g_wx[T_*B_*H3_];   // LN(x@Wx^T+b) precomputed
__device__ __align__(16) float g_wh[2*B_*H3_];    // double-buffered h@Wh^T (+bias) — sc1 mailbox
__device__ __align__(16) float g_pl[2*B_*H_];     // double-buffered plastic — sc1 mailbox
__device__ int g_bar[B_*BAR_STRIDE];              // init-barrier counters
__device__ int g_done[B_*BAR_STRIDE];             // completion counters
__device__ __align__(128) int g_flag[B_*BAR_STRIDE]; // 16 step-flags per group in ONE 64B line

__device__ __forceinline__ float sigmf(float v){ return 1.0f/(1.0f+__expf(-v)); }

// Coherent (agent-scope) accessors: per-access coherent, no cache-wide fences.
__device__ __forceinline__ void cstore(float* p, float v){
  __hip_atomic_store(p, v, __ATOMIC_RELAXED, __HIP_MEMORY_SCOPE_AGENT);
}
__device__ __forceinline__ float cload(const float* p){
  return __hip_atomic_load(p, __ATOMIC_RELAXED, __HIP_MEMORY_SCOPE_AGENT);
}
__device__ __forceinline__ void cstorei(int* p, int v){
  __hip_atomic_store(p, v, __ATOMIC_RELAXED, __HIP_MEMORY_SCOPE_AGENT);
}
__device__ __forceinline__ int cloadi(const int* p){
  return __hip_atomic_load(p, __ATOMIC_RELAXED, __HIP_MEMORY_SCOPE_AGENT);
}

// Steady-state group barrier, HARDENED:
//  - asm memory bookends: full compiler barriers — no mailbox load may hoist
//    above the poll, no mailbox store may sink below the arrival.
//  - explicit per-wave s_waitcnt(0): every wave's sc1 mailbox stores are acked
//    at the coherence point before it arrives, independent of how the
//    compiler lowers __syncthreads' workgroup-scope fences for agent atomics.
__device__ __forceinline__ void stepbar(int* flag, int c, int wv, int lane, int tag){
  asm volatile("" ::: "memory");
  __builtin_amdgcn_s_waitcnt(0);       // drain this wave's vmem (mailbox publish)
  __syncthreads();                     // all waves arrived => all stores acked
  if (threadIdx.x == 0) cstorei(&flag[c], tag);
  if (wv == 0 && lane < 16){
    while (cloadi(&flag[lane]) < tag) __builtin_amdgcn_s_sleep(1);
  }
  __syncthreads();
  asm volatile("" ::: "memory");
}

// Full barrier (init only): publishes plain g_wx stores via cache-wide fence.
__device__ __forceinline__ void groupbar_full(int* ctr, int target){
  asm volatile("" ::: "memory");
  __builtin_amdgcn_s_waitcnt(0);
  __syncthreads();
  if (threadIdx.x == 0){
    __threadfence();                   // release: wbl2 (flush plain g_wx writes)
    __hip_atomic_fetch_add(ctr, 1, __ATOMIC_RELAXED, __HIP_MEMORY_SCOPE_AGENT);
    while (__hip_atomic_load(ctr, __ATOMIC_RELAXED, __HIP_MEMORY_SCOPE_AGENT) < target)
      __builtin_amdgcn_s_sleep(1);
    __threadfence();                   // acquire: inv
  }
  __syncthreads();
  asm volatile("" ::: "memory");
}

// wrow LDS layout: row d at word 276*d; column e at word 276*d + 68*(e>>6) + (e&63).
#define WROW_STRIDE 276
#define WCHUNK 68
#define WMOD_STRIDE 260      // Wh2mod rows in LDS (pre-rotated chunk order)
#define WV_STRIDE 260        // clip rows in LDS

__global__ __launch_bounds__(256, 1) void sgru_kernel(
    const float* __restrict__ x,     const float* __restrict__ h0,
    const float* __restrict__ v0,    const float* __restrict__ dU0,
    const float* __restrict__ te0,   const float* __restrict__ tE0,
    const float* __restrict__ Wx2h,  const float* __restrict__ bx2h,
    const float* __restrict__ Wh2h,  const float* __restrict__ bh2h,
    const float* __restrict__ lnxg,  const float* __restrict__ lnxb,
    const float* __restrict__ lnhg,  const float* __restrict__ lnhb,
    const float* __restrict__ Wh2mod,const float* __restrict__ bh2mod,
    const float* __restrict__ Wmod2h,const float* __restrict__ bmod2h,
    const float* __restrict__ alpha, const float* __restrict__ tauU,
    float* __restrict__ out)
{
  const int tid  = threadIdx.x;
  const int g    = blockIdx.x;
  const int b    = g >> 4;   // batch
  const int c    = g & 15;   // chunk within batch group
  const int lane = tid & 63;
  const int wv   = tid >> 6;
  const int lane32 = tid & 31;

  __shared__ __align__(16) float hn_s[H_], ten_s[H_];
  __shared__ __align__(16) float lnhg_s[H3_], lnhb_s[H3_];
  __shared__ __align__(16) float wrow_s[48*WROW_STRIDE];
  __shared__ __align__(16) float wmod_s[R_*WMOD_STRIDE];  // Wh2mod, pre-rotated
  __shared__ __align__(16) float wv_s[16*WV_STRIDE];      // clip rows Wv for my 16 rows
  __shared__ __align__(16) float xr_s[3*I_];
  __shared__ float mod_s[R_];
  __shared__ float red_s[2][8];

  float* ws_wx = g_wx;
  float* ws_wh = g_wh;
  float* ws_pl = g_pl;
  int*   ctr   = g_bar  + b*BAR_STRIDE;
  int*   dctr  = g_done + b*BAR_STRIDE;
  int*   flag  = g_flag + b*BAR_STRIDE;   // flags [0..15] in one 64B line

  const float sp_a    = log1pf(__expf(alpha[0]));   // softplus(alpha)
  const float inv_spa = 1.0f / sp_a;
  const float tau     = sigmf(tauU[0]);

  // ---------------- init: states + weight staging ----------------
  hn_s[tid] = h0[b*H_+tid];
  float v_reg  = v0[b*H_+tid];
  float h_reg  = h0[b*H_+tid];
  float te_reg = te0[b*H_+tid];
  for (int idx = tid; idx < 48*256; idx += 256){
    int d = idx >> 8, e = idx & 255;
    wrow_s[d*WROW_STRIDE + WCHUNK*(e>>6) + (e&63)] = Wh2h[((size_t)(c*48 + d))*H_ + e];
  }
  // Wh2mod rows, stored with chunk order rotated by row: position f4=l8*8+j holds
  // source chunk (j+row&7)&7, so the scan-time read at linear index j is the
  // bank-spread access.
  for (int idx = tid; idx < R_*H_; idx += 256){
    int r = idx >> 8, rem = idx & 255;
    int f4 = rem >> 2, q = rem & 3;
    int l8s = f4 >> 3, j = f4 & 7;
    int srcc = (l8s*8 + ((j + (r&7)) & 7))*4 + q;
    wmod_s[r*WMOD_STRIDE + rem] = Wh2mod[r*H_ + srcc];
  }
  // clip rows (Wv) for my 16 owned rows
  for (int idx = tid; idx < 16*H_; idx += 256){
    int r = idx >> 8, e = idx & 255;
    wv_s[r*WV_STRIDE + e] = Wh2h[((size_t)(2*H_ + c*16 + r))*H_ + e];
  }
  for (int idx = tid; idx < H3_; idx += 256){
    lnhg_s[idx] = lnhg[idx];
    lnhb_s[idx] = lnhb[idx];
  }
  const int mk = tid >> 3;              // mod row 0..31
  const int l8 = tid & 7;
  const int mk7 = mk & 7;               // swizzle key (bank spread)
  const float bh2m = bh2mod[mk];
  const float wmA = Wmod2h[lane32];        // s-row weights (all waves)
  const float wmB = Wmod2h[R_ + lane32];   // m-row weights
  const float bm0 = bmod2h[0], bm1 = bmod2h[1];
  float bh2h_reg = 0.f;
  if (tid < 192) bh2h_reg = bh2h[c*48 + (tid>>2)];
  __syncthreads();

  // ---- init: Wx_ln rows t = c*3+q for batch b (carry-independent, precompute all T)
  // (high register pressure section — duR/tER deliberately loaded AFTER this)
  {
    for (int idx = tid; idx < 3*I_; idx += 256){
      int q = idx >> 7, e = idx & 127;
      xr_s[q*I_ + e] = x[((size_t)((c*3+q)*B_ + b))*I_ + e];
    }
    __syncthreads();
    float acc[3][3];
    #pragma unroll
    for (int k = 0; k < 3; k++){
      acc[k][0]=0.f; acc[k][1]=0.f; acc[k][2]=0.f;
      int f = tid + 256*k;
      const float4* wr = (const float4*)(Wx2h + (size_t)f*I_);
      for (int e4 = 0; e4 < I_/4; e4++){
        float4 w4 = wr[e4];
        int e = e4*4;
        #pragma unroll
        for (int q = 0; q < 3; q++){
          float t0 = fmaf(w4.x, xr_s[q*I_+e],   acc[k][q]);
          t0       = fmaf(w4.y, xr_s[q*I_+e+1], t0);
          t0       = fmaf(w4.z, xr_s[q*I_+e+2], t0);
          acc[k][q]= fmaf(w4.w, xr_s[q*I_+e+3], t0);
        }
      }
      float bf = bx2h[f];
      acc[k][0]+=bf; acc[k][1]+=bf; acc[k][2]+=bf;
    }
    for (int q = 0; q < 3; q++){
      float s1 = acc[0][q]+acc[1][q]+acc[2][q];
      float s2 = acc[0][q]*acc[0][q]+acc[1][q]*acc[1][q]+acc[2][q]*acc[2][q];
      #pragma unroll
      for (int off=32; off>0; off>>=1){ s1 += __shfl_xor(s1,off); s2 += __shfl_xor(s2,off); }
      if (lane==0){ red_s[0][wv]=s1; red_s[0][4+wv]=s2; }
      __syncthreads();
      s1 = red_s[0][0]+red_s[0][1]+red_s[0][2]+red_s[0][3];
      s2 = red_s[0][4]+red_s[0][5]+red_s[0][6]+red_s[0][7];
      __syncthreads();
      float mu  = s1*(1.0f/768.0f);
      float var = s2*(1.0f/768.0f) - mu*mu;
      float rs  = rsqrtf(var + 1e-5f);
      float* dst = ws_wx + ((size_t)((c*3+q)*B_ + b))*H3_;
      #pragma unroll
      for (int k = 0; k < 3; k++){
        int f = tid + 256*k;
        dst[f] = (acc[k][q]-mu)*rs*lnxg[f] + lnxb[f];
      }
    }
  }

  // persistent dU/tE fragments (my 16 rows) — loaded late to keep init pressure low
  float4 duR[4], tER[4];
  #pragma unroll
  for (int rr = 0; rr < 4; rr++){
    size_t rowo = ((size_t)(b*H_ + c*16 + rr*4 + wv))*H_;
    duR[rr] = ((const float4*)(dU0 + rowo))[lane];
    tER[rr] = ((const float4*)(tE0 + rowo))[lane];
  }

  // ---- init: plastic_0 = sp_a * dU0 @ h0; Wh_raw_0 (h0 is in hn_s)
  {
    const float4* h4 = (const float4*)hn_s;
    float4 hj = h4[lane];
    #pragma unroll
    for (int rr = 0; rr < 4; rr++){
      int i = c*16 + rr*4 + wv;
      float4 du = duR[rr];
      float acc = du.x*hj.x + du.y*hj.y + du.z*hj.z + du.w*hj.w;
      #pragma unroll
      for (int off=32; off>0; off>>=1) acc += __shfl_xor(acc,off);
      if (lane==0) cstore(&ws_pl[b*H_ + i], sp_a*acc);
    }
    if (tid < 192){
      int d = tid>>2, l4 = tid&3;
      const float4* wr4 = (const float4*)(wrow_s + d*WROW_STRIDE + WCHUNK*l4);
      const float4* hh4 = (const float4*)hn_s;
      float acc = 0.f;
      #pragma unroll
      for (int u = 0; u < 16; u++){
        float4 w4 = wr4[u];
        float4 hv = hh4[l4*16+u];
        acc = fmaf(w4.x,hv.x, fmaf(w4.y,hv.y, fmaf(w4.z,hv.z, fmaf(w4.w,hv.w, acc))));
      }
      acc += __shfl_xor(acc,1);
      acc += __shfl_xor(acc,2);
      if (l4==0) cstore(&ws_wh[b*H3_ + c*48 + d], acc + bh2h_reg);
    }
  }
  groupbar_full(ctr, 16);

  // ---------------- scan ----------------
  for (int t = 0; t < T_; t++){
    const int p  = t & 1;
    const int pn = p ^ 1;

    // ---- G phase (redundant across the 16 blocks of this batch group)
    float hn, ten;
    {
      const float* whr = ws_wh + p*(B_*H3_) + b*H3_;
      const float* pl  = ws_pl + p*(B_*H_)  + b*H_;
      float wh0 = cload(&whr[tid]);
      float wh1 = cload(&whr[tid+256]);
      float wh2 = cload(&whr[tid+512]) + cload(&pl[tid]);  // plastic pre-LN
      float s1 = wh0+wh1+wh2;
      float s2 = wh0*wh0+wh1*wh1+wh2*wh2;
      #pragma unroll
      for (int off=32; off>0; off>>=1){ s1 += __shfl_xor(s1,off); s2 += __shfl_xor(s2,off); }
      float* rb = red_s[p];
      if (lane==0){ rb[wv]=s1; rb[4+wv]=s2; }
      __syncthreads();                                     // (#1)
      s1 = rb[0]+rb[1]+rb[2]+rb[3];
      s2 = rb[4]+rb[5]+rb[6]+rb[7];
      float mu  = s1*(1.0f/768.0f);
      float var = s2*(1.0f/768.0f) - mu*mu;
      float rs  = rsqrtf(var + 1e-5f);
      const float* wxr = ws_wx + ((size_t)(t*B_ + b))*H3_;
      float pre0 = wxr[tid]     + (wh0-mu)*rs*lnhg_s[tid]     + lnhb_s[tid];
      float pre1 = wxr[tid+256] + (wh1-mu)*rs*lnhg_s[tid+256] + lnhb_s[tid+256];
      float pre2 = wxr[tid+512] + (wh2-mu)*rs*lnhg_s[tid+512] + lnhb_s[tid+512];
      // gates (all same-thread)
      float z  = sigmf(pre0);
      float r  = sigmf(pre1);
      float vn = fmaf(z, pre2 - v_reg, v_reg);
      hn  = fmaxf(vn, 0.0f);
      ten = fmaf(r, h_reg - te_reg, te_reg);
      v_reg = vn; h_reg = hn; te_reg = ten;
      hn_s[tid] = hn; ten_s[tid] = ten;
    }
    __syncthreads();                                       // (#2) hn_s/ten_s ready

    // ---- Wh_raw for t+1 EARLY: sc1 store latency overlaps mod+U compute
    if (t < T_-1 && tid < 192){
      int d = tid>>2, l4 = tid&3;
      const float4* wr4 = (const float4*)(wrow_s + d*WROW_STRIDE + WCHUNK*l4);
      const float4* hh4 = (const float4*)hn_s;
      float acc = 0.f;
      #pragma unroll
      for (int u = 0; u < 16; u++){
        float4 w4 = wr4[u];
        float4 hv = hh4[l4*16+u];
        acc = fmaf(w4.x,hv.x, fmaf(w4.y,hv.y, fmaf(w4.z,hv.z, fmaf(w4.w,hv.w, acc))));
      }
      acc += __shfl_xor(acc,1);
      acc += __shfl_xor(acc,2);
      if (l4==0) cstore(&ws_wh[pn*(B_*H3_) + b*H3_ + c*48 + d], acc + bh2h_reg);
    }
    if (c == 0)
      out[OFF_OUTS + ((size_t)(t*B_+b))*H_ + tid] = hn;

    // ---- mod = relu(h_new @ Wh2mod^T + b); W from LDS (pre-rotated), hn rotated
    {
      const float4* hn4 = (const float4*)hn_s;
      const float4* wrow = (const float4*)(wmod_s + mk*WMOD_STRIDE);
      float acc = 0.f;
      #pragma unroll
      for (int j = 0; j < 8; j++){
        float4 hv = hn4[l8*8 + ((j+mk7)&7)];
        float4 w4 = wrow[l8*8 + j];
        acc = fmaf(w4.x,hv.x, fmaf(w4.y,hv.y, fmaf(w4.z,hv.z, fmaf(w4.w,hv.w, acc))));
      }
      acc += __shfl_xor(acc,1); acc += __shfl_xor(acc,2); acc += __shfl_xor(acc,4);
      if (l8==0) mod_s[mk] = fmaxf(acc + bh2m, 0.0f);
    }
    __syncthreads();                                       // (#3) mod_s ready

    // ---- s,m per-wave in registers (no sm_s, no extra sync)
    float s_b, m_b;
    {
      float mv = mod_s[lane32];
      float p0 = mv*wmA, p1 = mv*wmB;
      #pragma unroll
      for (int off=16; off>0; off>>=1){ p0 += __shfl_xor(p0,off); p1 += __shfl_xor(p1,off); }
      s_b = sigmf(p0+bm0);
      m_b = p1+bm1;
    }
    if (c == 0){
      if (tid < R_) out[OFF_MODS + (size_t)(t*B_+b)*R_ + tid] = mod_s[tid];
      if (t == T_-1){
        out[OFF_V  + b*H_ + tid] = v_reg;
        out[OFF_H  + b*H_ + tid] = h_reg;
        out[OFF_TE + b*H_ + tid] = te_reg;
      }
    }

    // ---- U phase: register-resident tE/dU update for my 16 rows,
    //      fused plastic_{t+1}; clip row from LDS; global write ONLY at t=47.
    {
      const float4* hn4 = (const float4*)hn_s;
      const float4* te4 = (const float4*)ten_s;
      float4 hj = hn4[lane];
      float4 tj = te4[lane];
      #pragma unroll
      for (int rr = 0; rr < 4; rr++){
        int i = c*16 + rr*4 + wv;
        float4 du = duR[rr];
        float4 tE = tER[rr];
        float4 w  = ((const float4*)(wv_s + (rr*4+wv)*WV_STRIDE))[lane];
        float hni  = hn_s[i];
        float teni = ten_s[i];
        float4 nd, nt;
        float acc;
        { float o_ = hni*tj.x - teni*hj.x;
          float tn = fmaf(s_b, o_ - tE.x, tE.x);
          float dn = fmaf(tau, fmaf(m_b, tn, -du.x), du.x);
          float up =  fmaxf(1.0f - w.x, 0.0f)*inv_spa;
          float lo = -fmaxf(1.0f + w.x, 0.0f)*inv_spa;
          dn = fminf(dn, up); dn = fmaxf(dn, lo);
          nt.x = tn; nd.x = dn; acc = dn*hj.x; }
        { float o_ = hni*tj.y - teni*hj.y;
          float tn = fmaf(s_b, o_ - tE.y, tE.y);
          float dn = fmaf(tau, fmaf(m_b, tn, -du.y), du.y);
          float up =  fmaxf(1.0f - w.y, 0.0f)*inv_spa;
          float lo = -fmaxf(1.0f + w.y, 0.0f)*inv_spa;
          dn = fminf(dn, up); dn = fmaxf(dn, lo);
          nt.y = tn; nd.y = dn; acc = fmaf(dn, hj.y, acc); }
        { float o_ = hni*tj.z - teni*hj.z;
          float tn = fmaf(s_b, o_ - tE.z, tE.z);
          float dn = fmaf(tau, fmaf(m_b, tn, -du.z), du.z);
          float up =  fmaxf(1.0f - w.z, 0.0f)*inv_spa;
          float lo = -fmaxf(1.0f + w.z, 0.0f)*inv_spa;
          dn = fminf(dn, up); dn = fmaxf(dn, lo);
          nt.z = tn; nd.z = dn; acc = fmaf(dn, hj.z, acc); }
        { float o_ = hni*tj.w - teni*hj.w;
          float tn = fmaf(s_b, o_ - tE.w, tE.w);
          float dn = fmaf(tau, fmaf(m_b, tn, -du.w), du.w);
          float up =  fmaxf(1.0f - w.w, 0.0f)*inv_spa;
          float lo = -fmaxf(1.0f + w.w, 0.0f)*inv_spa;
          dn = fminf(dn, up); dn = fmaxf(dn, lo);
          nt.w = tn; nd.w = dn; acc = fmaf(dn, hj.w, acc); }
        duR[rr] = nd;
        tER[rr] = nt;
        if (t == T_-1){
          size_t rowo = ((size_t)(b*H_ + i))*H_;
          ((float4*)(out + OFF_DU + rowo))[lane] = nd;
          ((float4*)(out + OFF_TT + rowo))[lane] = nt;
        } else {
          #pragma unroll
          for (int off=32; off>0; off>>=1) acc += __shfl_xor(acc,off);
          if (lane==0) cstore(&ws_pl[pn*(B_*H_) + b*H_ + i], sp_a*acc);  // plastic t+1
        }
      }
    }

    // ---- hardened flag-line barrier
    if (t < T_-1)
      stepbar(flag, c, wv, lane, t + 1);
  }

  // ---- self-reset of group counters/flags for the next launch.
  __syncthreads();
  if (threadIdx.x == 0){
    int d = __hip_atomic_fetch_add(dctr, 1, __ATOMIC_RELAXED, __HIP_MEMORY_SCOPE_AGENT);
    if (d == 15){
      __hip_atomic_store(ctr,  0, __ATOMIC_RELAXED, __HIP_MEMORY_SCOPE_AGENT);
      __hip_atomic_store(dctr, 0, __ATOMIC_RELAXED, __HIP_MEMORY_SCOPE_AGENT);
      for (int k = 0; k < 16; k++)
        cstorei(&flag[k], 0);
    }
  }
}

extern "C" void kernel_launch(void* const* d_in, const int* in_sizes, int n_in,
                              void* d_out, int out_size, void* d_ws, size_t ws_size,
                              hipStream_t stream)
{
  const float* x      = (const float*)d_in[0];
  const float* h0     = (const float*)d_in[1];
  const float* v0     = (const float*)d_in[2];
  const float* dU0    = (const float*)d_in[3];
  const float* te0    = (const float*)d_in[4];
  const float* tE0    = (const float*)d_in[5];
  const float* Wx2h   = (const float*)d_in[6];
  const float* bx2h   = (const float*)d_in[7];
  const float* Wh2h   = (const float*)d_in[8];
  const float* bh2h   = (const float*)d_in[9];
  const float* lnxg   = (const float*)d_in[10];
  const float* lnxb   = (const float*)d_in[11];
  const float* lnhg   = (const float*)d_in[12];
  const float* lnhb   = (const float*)d_in[13];
  const float* Wh2mod = (const float*)d_in[14];
  const float* bh2mod = (const float*)d_in[15];
  const float* Wmod2h = (const float*)d_in[16];
  const float* bmod2h = (const float*)d_in[17];
  const float* alpha  = (const float*)d_in[18];
  const float* tauU   = (const float*)d_in[19];
  float* out = (float*)d_out;

  sgru_kernel<<<dim3(256), dim3(256), 0, stream>>>(
      x, h0, v0, dU0, te0, tE0, Wx2h, bx2h, Wh2h, bh2h,
      lnxg, lnxb, lnhg, lnhb, Wh2mod, bh2mod, Wmod2h, bmod2h,
      alpha, tauU, out);
}

// Round 10
// 374.066 us; speedup vs baseline: 1.0849x; 1.0849x over previous
//
#include <hip/hip_runtime.h>

// Problem dims
#define H_  256
#define I_  128
#define R_  32
#define B_  16
#define T_  48
#define H3_ 768

// d_out float offsets: (v, h, dU, trace_e, trace_E, outs, mods)
#define OFF_V    0
#define OFF_H    4096
#define OFF_DU   8192
#define OFF_TE   1056768
#define OFF_TT   1060864
#define OFF_OUTS 2109440
#define OFF_MODS 2306048

#define BAR_STRIDE 32          // ints; 128B between per-group structures

// Module-static scratch (allocated at .so load; zero-init counters).
__device__ __align__(16) float g_wx[T_*B_*H3_];   // LN(x@Wx^T+b) precomputed
__device__ __align__(16) float g_wh[2*B_*H3_];    // double-buffered h@Wh^T (+bias) — sc1 mailbox
__device__ __align__(16) float g_pl[2*B_*H_];     // double-buffered plastic — sc1 mailbox
__device__ int g_bar[B_*BAR_STRIDE];              // init-barrier counters
__device__ int g_done[B_*BAR_STRIDE];             // completion counters
__device__ __align__(128) int g_flag[B_*BAR_STRIDE]; // 16 step-flags per group in ONE 64B line

__device__ __forceinline__ float sigmf(float v){ return 1.0f/(1.0f+__expf(-v)); }

// Coherent (agent-scope) accessors: per-access coherent, no cache-wide fences.
__device__ __forceinline__ void cstore(float* p, float v){
  __hip_atomic_store(p, v, __ATOMIC_RELAXED, __HIP_MEMORY_SCOPE_AGENT);
}
__device__ __forceinline__ float cload(const float* p){
  return __hip_atomic_load(p, __ATOMIC_RELAXED, __HIP_MEMORY_SCOPE_AGENT);
}
__device__ __forceinline__ void cstorei(int* p, int v){
  __hip_atomic_store(p, v, __ATOMIC_RELAXED, __HIP_MEMORY_SCOPE_AGENT);
}
__device__ __forceinline__ int cloadi(const int* p){
  return __hip_atomic_load(p, __ATOMIC_RELAXED, __HIP_MEMORY_SCOPE_AGENT);
}

// Steady-state group barrier, HARDENED (see round 9 notes):
//  - asm memory bookends: full compiler barriers.
//  - explicit per-wave s_waitcnt(0): sc1 mailbox stores acked at the
//    device coherence point before arrival.
__device__ __forceinline__ void stepbar(int* flag, int c, int wv, int lane, int tag){
  asm volatile("" ::: "memory");
  __builtin_amdgcn_s_waitcnt(0);       // drain this wave's vmem (mailbox publish)
  __syncthreads();                     // all waves arrived => all stores acked
  if (threadIdx.x == 0) cstorei(&flag[c], tag);
  if (wv == 0 && lane < 16){
    while (cloadi(&flag[lane]) < tag) __builtin_amdgcn_s_sleep(1);
  }
  __syncthreads();
  asm volatile("" ::: "memory");
}

// Full barrier (init only): publishes plain g_wx stores via cache-wide fence.
__device__ __forceinline__ void groupbar_full(int* ctr, int target){
  asm volatile("" ::: "memory");
  __builtin_amdgcn_s_waitcnt(0);
  __syncthreads();
  if (threadIdx.x == 0){
    __threadfence();                   // release: wbl2 (flush plain g_wx writes)
    __hip_atomic_fetch_add(ctr, 1, __ATOMIC_RELAXED, __HIP_MEMORY_SCOPE_AGENT);
    while (__hip_atomic_load(ctr, __ATOMIC_RELAXED, __HIP_MEMORY_SCOPE_AGENT) < target)
      __builtin_amdgcn_s_sleep(1);
    __threadfence();                   // acquire: inv
  }
  __syncthreads();
  asm volatile("" ::: "memory");
}

// wrow LDS layout: row d at word 276*d; column e at word 276*d + 68*(e>>6) + (e&63).
#define WROW_STRIDE 276
#define WCHUNK 68
#define WMOD_STRIDE 260      // Wh2mod rows in LDS (pre-rotated chunk order)
#define WV_STRIDE 260        // clip rows in LDS

__global__ __launch_bounds__(256, 1) void sgru_kernel(
    const float* __restrict__ x,     const float* __restrict__ h0,
    const float* __restrict__ v0,    const float* __restrict__ dU0,
    const float* __restrict__ te0,   const float* __restrict__ tE0,
    const float* __restrict__ Wx2h,  const float* __restrict__ bx2h,
    const float* __restrict__ Wh2h,  const float* __restrict__ bh2h,
    const float* __restrict__ lnxg,  const float* __restrict__ lnxb,
    const float* __restrict__ lnhg,  const float* __restrict__ lnhb,
    const float* __restrict__ Wh2mod,const float* __restrict__ bh2mod,
    const float* __restrict__ Wmod2h,const float* __restrict__ bmod2h,
    const float* __restrict__ alpha, const float* __restrict__ tauU,
    float* __restrict__ out)
{
  const int tid  = threadIdx.x;
  const int g    = blockIdx.x;
  const int b    = g >> 4;   // batch
  const int c    = g & 15;   // chunk within batch group
  const int lane = tid & 63;
  const int wv   = tid >> 6;
  const int lane32 = tid & 31;

  __shared__ __align__(16) float hn_s[H_], ten_s[H_];
  __shared__ __align__(16) float lnhg_s[H3_], lnhb_s[H3_];
  __shared__ __align__(16) float wrow_s[48*WROW_STRIDE];
  __shared__ __align__(16) float wmod_s[R_*WMOD_STRIDE];  // Wh2mod, pre-rotated
  __shared__ __align__(16) float wv_s[16*WV_STRIDE];      // clip rows Wv for my 16 rows
  __shared__ __align__(16) float xr_s[3*I_];
  __shared__ float mod_s[R_];
  __shared__ float red_s[2][8];

  float* ws_wx = g_wx;
  float* ws_wh = g_wh;
  float* ws_pl = g_pl;
  int*   ctr   = g_bar  + b*BAR_STRIDE;
  int*   dctr  = g_done + b*BAR_STRIDE;
  int*   flag  = g_flag + b*BAR_STRIDE;   // flags [0..15] in one 64B line

  const float sp_a    = log1pf(__expf(alpha[0]));   // softplus(alpha)
  const float inv_spa = 1.0f / sp_a;
  const float tau     = sigmf(tauU[0]);

  // ---------------- init: states + weight staging ----------------
  hn_s[tid] = h0[b*H_+tid];
  float v_reg  = v0[b*H_+tid];
  float h_reg  = h0[b*H_+tid];
  float te_reg = te0[b*H_+tid];
  #pragma clang loop unroll_count(4)
  for (int idx = tid; idx < 48*256; idx += 256){
    int d = idx >> 8, e = idx & 255;
    wrow_s[d*WROW_STRIDE + WCHUNK*(e>>6) + (e&63)] = Wh2h[((size_t)(c*48 + d))*H_ + e];
  }
  // Wh2mod rows, stored with chunk order rotated by row.
  #pragma clang loop unroll_count(4)
  for (int idx = tid; idx < R_*H_; idx += 256){
    int r = idx >> 8, rem = idx & 255;
    int f4 = rem >> 2, q = rem & 3;
    int l8s = f4 >> 3, j = f4 & 7;
    int srcc = (l8s*8 + ((j + (r&7)) & 7))*4 + q;
    wmod_s[r*WMOD_STRIDE + rem] = Wh2mod[r*H_ + srcc];
  }
  // clip rows (Wv) for my 16 owned rows
  #pragma clang loop unroll_count(4)
  for (int idx = tid; idx < 16*H_; idx += 256){
    int r = idx >> 8, e = idx & 255;
    wv_s[r*WV_STRIDE + e] = Wh2h[((size_t)(2*H_ + c*16 + r))*H_ + e];
  }
  for (int idx = tid; idx < H3_; idx += 256){
    lnhg_s[idx] = lnhg[idx];
    lnhb_s[idx] = lnhb[idx];
  }
  const int mk = tid >> 3;              // mod row 0..31
  const int l8 = tid & 7;
  const int mk7 = mk & 7;               // swizzle key (bank spread)
  const float bh2m = bh2mod[mk];
  const float wmA = Wmod2h[lane32];        // s-row weights (all waves)
  const float wmB = Wmod2h[R_ + lane32];   // m-row weights
  const float bm0 = bmod2h[0], bm1 = bmod2h[1];
  float bh2h_reg = 0.f;
  if (tid < 192) bh2h_reg = bh2h[c*48 + (tid>>2)];
  __syncthreads();

  // ---- init: Wx_ln rows t = c*3+q for batch b (carry-independent, precompute all T)
  // (duR/tER deliberately loaded AFTER this; e4 unroll capped to bound pressure)
  {
    for (int idx = tid; idx < 3*I_; idx += 256){
      int q = idx >> 7, e = idx & 127;
      xr_s[q*I_ + e] = x[((size_t)((c*3+q)*B_ + b))*I_ + e];
    }
    __syncthreads();
    float acc[3][3];
    #pragma unroll
    for (int k = 0; k < 3; k++){
      acc[k][0]=0.f; acc[k][1]=0.f; acc[k][2]=0.f;
      int f = tid + 256*k;
      const float4* wr = (const float4*)(Wx2h + (size_t)f*I_);
      #pragma clang loop unroll_count(4)
      for (int e4 = 0; e4 < I_/4; e4++){
        float4 w4 = wr[e4];
        int e = e4*4;
        #pragma unroll
        for (int q = 0; q < 3; q++){
          float t0 = fmaf(w4.x, xr_s[q*I_+e],   acc[k][q]);
          t0       = fmaf(w4.y, xr_s[q*I_+e+1], t0);
          t0       = fmaf(w4.z, xr_s[q*I_+e+2], t0);
          acc[k][q]= fmaf(w4.w, xr_s[q*I_+e+3], t0);
        }
      }
      float bf = bx2h[f];
      acc[k][0]+=bf; acc[k][1]+=bf; acc[k][2]+=bf;
    }
    for (int q = 0; q < 3; q++){
      float s1 = acc[0][q]+acc[1][q]+acc[2][q];
      float s2 = acc[0][q]*acc[0][q]+acc[1][q]*acc[1][q]+acc[2][q]*acc[2][q];
      #pragma unroll
      for (int off=32; off>0; off>>=1){ s1 += __shfl_xor(s1,off); s2 += __shfl_xor(s2,off); }
      if (lane==0){ red_s[0][wv]=s1; red_s[0][4+wv]=s2; }
      __syncthreads();
      s1 = red_s[0][0]+red_s[0][1]+red_s[0][2]+red_s[0][3];
      s2 = red_s[0][4]+red_s[0][5]+red_s[0][6]+red_s[0][7];
      __syncthreads();
      float mu  = s1*(1.0f/768.0f);
      float var = s2*(1.0f/768.0f) - mu*mu;
      float rs  = rsqrtf(var + 1e-5f);
      float* dst = ws_wx + ((size_t)((c*3+q)*B_ + b))*H3_;
      #pragma unroll
      for (int k = 0; k < 3; k++){
        int f = tid + 256*k;
        dst[f] = (acc[k][q]-mu)*rs*lnxg[f] + lnxb[f];
      }
    }
  }

  // persistent dU/tE fragments (my 16 rows) — loaded late to keep init pressure low
  float4 duR[4], tER[4];
  #pragma unroll
  for (int rr = 0; rr < 4; rr++){
    size_t rowo = ((size_t)(b*H_ + c*16 + rr*4 + wv))*H_;
    duR[rr] = ((const float4*)(dU0 + rowo))[lane];
    tER[rr] = ((const float4*)(tE0 + rowo))[lane];
  }

  // ---- init: plastic_0 = sp_a * dU0 @ h0; Wh_raw_0 (h0 is in hn_s)
  {
    const float4* h4 = (const float4*)hn_s;
    float4 hj = h4[lane];
    #pragma unroll
    for (int rr = 0; rr < 4; rr++){
      int i = c*16 + rr*4 + wv;
      float4 du = duR[rr];
      float acc = du.x*hj.x + du.y*hj.y + du.z*hj.z + du.w*hj.w;
      #pragma unroll
      for (int off=32; off>0; off>>=1) acc += __shfl_xor(acc,off);
      if (lane==0) cstore(&ws_pl[b*H_ + i], sp_a*acc);
    }
    if (tid < 192){
      int d = tid>>2, l4 = tid&3;
      const float4* wr4 = (const float4*)(wrow_s + d*WROW_STRIDE + WCHUNK*l4);
      const float4* hh4 = (const float4*)hn_s;
      float acc = 0.f;
      #pragma unroll
      for (int u = 0; u < 16; u++){
        float4 w4 = wr4[u];
        float4 hv = hh4[l4*16+u];
        acc = fmaf(w4.x,hv.x, fmaf(w4.y,hv.y, fmaf(w4.z,hv.z, fmaf(w4.w,hv.w, acc))));
      }
      acc += __shfl_xor(acc,1);
      acc += __shfl_xor(acc,2);
      if (l4==0) cstore(&ws_wh[b*H3_ + c*48 + d], acc + bh2h_reg);
    }
  }
  groupbar_full(ctr, 16);

  // ---------------- scan ----------------
  #pragma clang loop unroll(disable)
  for (int t = 0; t < T_; t++){
    const int p  = t & 1;
    const int pn = p ^ 1;

    // ---- G phase (redundant across the 16 blocks of this batch group)
    float hn, ten;
    {
      const float* whr = ws_wh + p*(B_*H3_) + b*H3_;
      const float* pl  = ws_pl + p*(B_*H_)  + b*H_;
      float wh0 = cload(&whr[tid]);
      float wh1 = cload(&whr[tid+256]);
      float wh2 = cload(&whr[tid+512]) + cload(&pl[tid]);  // plastic pre-LN
      float s1 = wh0+wh1+wh2;
      float s2 = wh0*wh0+wh1*wh1+wh2*wh2;
      #pragma unroll
      for (int off=32; off>0; off>>=1){ s1 += __shfl_xor(s1,off); s2 += __shfl_xor(s2,off); }
      float* rb = red_s[p];
      if (lane==0){ rb[wv]=s1; rb[4+wv]=s2; }
      __syncthreads();                                     // (#1)
      s1 = rb[0]+rb[1]+rb[2]+rb[3];
      s2 = rb[4]+rb[5]+rb[6]+rb[7];
      float mu  = s1*(1.0f/768.0f);
      float var = s2*(1.0f/768.0f) - mu*mu;
      float rs  = rsqrtf(var + 1e-5f);
      const float* wxr = ws_wx + ((size_t)(t*B_ + b))*H3_;
      float pre0 = wxr[tid]     + (wh0-mu)*rs*lnhg_s[tid]     + lnhb_s[tid];
      float pre1 = wxr[tid+256] + (wh1-mu)*rs*lnhg_s[tid+256] + lnhb_s[tid+256];
      float pre2 = wxr[tid+512] + (wh2-mu)*rs*lnhg_s[tid+512] + lnhb_s[tid+512];
      // gates (all same-thread)
      float z  = sigmf(pre0);
      float r  = sigmf(pre1);
      float vn = fmaf(z, pre2 - v_reg, v_reg);
      hn  = fmaxf(vn, 0.0f);
      ten = fmaf(r, h_reg - te_reg, te_reg);
      v_reg = vn; h_reg = hn; te_reg = ten;
      hn_s[tid] = hn; ten_s[tid] = ten;
    }
    __syncthreads();                                       // (#2) hn_s/ten_s ready

    // ---- Wh_raw for t+1 EARLY: sc1 store latency overlaps mod+U compute
    if (t < T_-1 && tid < 192){
      int d = tid>>2, l4 = tid&3;
      const float4* wr4 = (const float4*)(wrow_s + d*WROW_STRIDE + WCHUNK*l4);
      const float4* hh4 = (const float4*)hn_s;
      float acc = 0.f;
      #pragma unroll
      for (int u = 0; u < 16; u++){
        float4 w4 = wr4[u];
        float4 hv = hh4[l4*16+u];
        acc = fmaf(w4.x,hv.x, fmaf(w4.y,hv.y, fmaf(w4.z,hv.z, fmaf(w4.w,hv.w, acc))));
      }
      acc += __shfl_xor(acc,1);
      acc += __shfl_xor(acc,2);
      if (l4==0) cstore(&ws_wh[pn*(B_*H3_) + b*H3_ + c*48 + d], acc + bh2h_reg);
    }
    if (c == 0)
      out[OFF_OUTS + ((size_t)(t*B_+b))*H_ + tid] = hn;

    // ---- mod = relu(h_new @ Wh2mod^T + b); W from LDS (pre-rotated), hn rotated
    {
      const float4* hn4 = (const float4*)hn_s;
      const float4* wrow = (const float4*)(wmod_s + mk*WMOD_STRIDE);
      float acc = 0.f;
      #pragma unroll
      for (int j = 0; j < 8; j++){
        float4 hv = hn4[l8*8 + ((j+mk7)&7)];
        float4 w4 = wrow[l8*8 + j];
        acc = fmaf(w4.x,hv.x, fmaf(w4.y,hv.y, fmaf(w4.z,hv.z, fmaf(w4.w,hv.w, acc))));
      }
      acc += __shfl_xor(acc,1); acc += __shfl_xor(acc,2); acc += __shfl_xor(acc,4);
      if (l8==0) mod_s[mk] = fmaxf(acc + bh2m, 0.0f);
    }
    __syncthreads();                                       // (#3) mod_s ready

    // ---- s,m per-wave in registers (no sm_s, no extra sync)
    float s_b, m_b;
    {
      float mv = mod_s[lane32];
      float p0 = mv*wmA, p1 = mv*wmB;
      #pragma unroll
      for (int off=16; off>0; off>>=1){ p0 += __shfl_xor(p0,off); p1 += __shfl_xor(p1,off); }
      s_b = sigmf(p0+bm0);
      m_b = p1+bm1;
    }
    if (c == 0){
      if (tid < R_) out[OFF_MODS + (size_t)(t*B_+b)*R_ + tid] = mod_s[tid];
      if (t == T_-1){
        out[OFF_V  + b*H_ + tid] = v_reg;
        out[OFF_H  + b*H_ + tid] = h_reg;
        out[OFF_TE + b*H_ + tid] = te_reg;
      }
    }

    // ---- U phase: register-resident tE/dU update for my 16 rows,
    //      fused plastic_{t+1}; clip row from LDS; global write ONLY at t=47.
    {
      const float4* hn4 = (const float4*)hn_s;
      const float4* te4 = (const float4*)ten_s;
      float4 hj = hn4[lane];
      float4 tj = te4[lane];
      #pragma unroll
      for (int rr = 0; rr < 4; rr++){
        int i = c*16 + rr*4 + wv;
        float4 du = duR[rr];
        float4 tE = tER[rr];
        float4 w  = ((const float4*)(wv_s + (rr*4+wv)*WV_STRIDE))[lane];
        float hni  = hn_s[i];
        float teni = ten_s[i];
        float4 nd, nt;
        float acc;
        { float o_ = hni*tj.x - teni*hj.x;
          float tn = fmaf(s_b, o_ - tE.x, tE.x);
          float dn = fmaf(tau, fmaf(m_b, tn, -du.x), du.x);
          float up =  fmaxf(1.0f - w.x, 0.0f)*inv_spa;
          float lo = -fmaxf(1.0f + w.x, 0.0f)*inv_spa;
          dn = fminf(dn, up); dn = fmaxf(dn, lo);
          nt.x = tn; nd.x = dn; acc = dn*hj.x; }
        { float o_ = hni*tj.y - teni*hj.y;
          float tn = fmaf(s_b, o_ - tE.y, tE.y);
          float dn = fmaf(tau, fmaf(m_b, tn, -du.y), du.y);
          float up =  fmaxf(1.0f - w.y, 0.0f)*inv_spa;
          float lo = -fmaxf(1.0f + w.y, 0.0f)*inv_spa;
          dn = fminf(dn, up); dn = fmaxf(dn, lo);
          nt.y = tn; nd.y = dn; acc = fmaf(dn, hj.y, acc); }
        { float o_ = hni*tj.z - teni*hj.z;
          float tn = fmaf(s_b, o_ - tE.z, tE.z);
          float dn = fmaf(tau, fmaf(m_b, tn, -du.z), du.z);
          float up =  fmaxf(1.0f - w.z, 0.0f)*inv_spa;
          float lo = -fmaxf(1.0f + w.z, 0.0f)*inv_spa;
          dn = fminf(dn, up); dn = fmaxf(dn, lo);
          nt.z = tn; nd.z = dn; acc = fmaf(dn, hj.z, acc); }
        { float o_ = hni*tj.w - teni*hj.w;
          float tn = fmaf(s_b, o_ - tE.w, tE.w);
          float dn = fmaf(tau, fmaf(m_b, tn, -du.w), du.w);
          float up =  fmaxf(1.0f - w.w, 0.0f)*inv_spa;
          float lo = -fmaxf(1.0f + w.w, 0.0f)*inv_spa;
          dn = fminf(dn, up); dn = fmaxf(dn, lo);
          nt.w = tn; nd.w = dn; acc = fmaf(dn, hj.w, acc); }
        duR[rr] = nd;
        tER[rr] = nt;
        if (t == T_-1){
          size_t rowo = ((size_t)(b*H_ + i))*H_;
          ((float4*)(out + OFF_DU + rowo))[lane] = nd;
          ((float4*)(out + OFF_TT + rowo))[lane] = nt;
        } else {
          #pragma unroll
          for (int off=32; off>0; off>>=1) acc += __shfl_xor(acc,off);
          if (lane==0) cstore(&ws_pl[pn*(B_*H_) + b*H_ + i], sp_a*acc);  // plastic t+1
        }
      }
    }

    // ---- hardened flag-line barrier
    if (t < T_-1)
      stepbar(flag, c, wv, lane, t + 1);
  }

  // ---- self-reset of group counters/flags for the next launch.
  __syncthreads();
  if (threadIdx.x == 0){
    int d = __hip_atomic_fetch_add(dctr, 1, __ATOMIC_RELAXED, __HIP_MEMORY_SCOPE_AGENT);
    if (d == 15){
      __hip_atomic_store(ctr,  0, __ATOMIC_RELAXED, __HIP_MEMORY_SCOPE_AGENT);
      __hip_atomic_store(dctr, 0, __ATOMIC_RELAXED, __HIP_MEMORY_SCOPE_AGENT);
      for (int k = 0; k < 16; k++)
        cstorei(&flag[k], 0);
    }
  }
}

extern "C" void kernel_launch(void* const* d_in, const int* in_sizes, int n_in,
                              void* d_out, int out_size, void* d_ws, size_t ws_size,
                              hipStream_t stream)
{
  const float* x      = (const float*)d_in[0];
  const float* h0     = (const float*)d_in[1];
  const float* v0     = (const float*)d_in[2];
  const float* dU0    = (const float*)d_in[3];
  const float* te0    = (const float*)d_in[4];
  const float* tE0    = (const float*)d_in[5];
  const float* Wx2h   = (const float*)d_in[6];
  const float* bx2h   = (const float*)d_in[7];
  const float* Wh2h   = (const float*)d_in[8];
  const float* bh2h   = (const float*)d_in[9];
  const float* lnxg   = (const float*)d_in[10];
  const float* lnxb   = (const float*)d_in[11];
  const float* lnhg   = (const float*)d_in[12];
  const float* lnhb   = (const float*)d_in[13];
  const float* Wh2mod = (const float*)d_in[14];
  const float* bh2mod = (const float*)d_in[15];
  const float* Wmod2h = (const float*)d_in[16];
  const float* bmod2h = (const float*)d_in[17];
  const float* alpha  = (const float*)d_in[18];
  const float* tauU   = (const float*)d_in[19];
  float* out = (float*)d_out;

  sgru_kernel<<<dim3(256), dim3(256), 0, stream>>>(
      x, h0, v0, dU0, te0, tE0, Wx2h, bx2h, Wh2h, bh2h,
      lnxg, lnxb, lnhg, lnhb, Wh2mod, bh2mod, Wmod2h, bmod2h,
      alpha, tauU, out);
}